// Round 3
// baseline (731.205 us; speedup 1.0000x reference)
//
#include <hip/hip_runtime.h>
#include <math.h>

#define T_STEPS 16
#define NTOK 2048
#define WAVES_PER_BLOCK 8
#define BLOCK (WAVES_PER_BLOCK * 64)
#define KBLK (NTOK / 64)   // 32 k-blocks of 64 tokens

// approx sqrt(q) = q * rsqrt_hack(q); rel err <= 3.42% (Lomont), full-rate only
__device__ __forceinline__ float approx_sqrt(float q) {
    float y = __uint_as_float(0x5f3759dfu - (__float_as_uint(q) >> 1));
    return q * y;
}

__global__ __launch_bounds__(BLOCK, 4)
void tokenizer_kernel(const float* __restrict__ data,
                      const float* __restrict__ tok,
                      float* __restrict__ out,
                      int B) {
    __shared__ float4 ldsA[NTOK];   // corners 0,1: (x0,y0,x1,y1)
    __shared__ float4 ldsB[NTOK];   // corners 2,3: (x2,y2,x3,y3)

    const float4* src = (const float4*)tok;
    for (int j = threadIdx.x; j < 2 * NTOK; j += BLOCK) {
        float4 v = src[j];
        if (j & 1) ldsB[j >> 1] = v;
        else       ldsA[j >> 1] = v;
    }
    __syncthreads();

    const int wave = threadIdx.x >> 6;
    const int lane = threadIdx.x & 63;
    const int b = blockIdx.x * WAVES_PER_BLOCK + wave;
    if (b >= B) return;

    const float* db = data + (size_t)b * (T_STEPS * 3);
    float* outIdx  = out;
    float* outPos  = out + (size_t)B * T_STEPS;
    float* outHead = out + (size_t)B * T_STEPS * 3;

    float cpx = 0.f, cpy = 0.f;    // carry: prev_pos
    float rc = 1.f, rs = 0.f;      // carry: cos/sin(prev_head)

    for (int t = 0; t < T_STEPS; ++t) {
        const float px = db[t * 3 + 0];
        const float py = db[t * 3 + 1];
        const float hh = db[t * 3 + 2];

        // gt contour corners (lf, rf, rb, lb)
        float sh, ch;
        sincosf(hh, &sh, &ch);
        const float hc = 0.5f * ch, hs = 0.5f * sh;
        const float lc = 4.8f * hc, ls = 4.8f * hs;
        const float wc = 2.0f * hc, ws = 2.0f * hs;

        // e_j = cp - g_j ; u_j = R^T e_j   (R = [[c,-s],[s,c]])
        // => dist_j = || R f_j + e_j || = || f_j + u_j ||
        const float e0x = cpx - (px + lc - ws), e0y = cpy - (py + ls + wc);
        const float e1x = cpx - (px + lc + ws), e1y = cpy - (py + ls - wc);
        const float e2x = cpx - (px - lc + ws), e2y = cpy - (py - ls - wc);
        const float e3x = cpx - (px - lc - ws), e3y = cpy - (py - ls + wc);
        const float u0x = rc * e0x + rs * e0y, u0y = rc * e0y - rs * e0x;
        const float u1x = rc * e1x + rs * e1y, u1y = rc * e1y - rs * e1x;
        const float u2x = rc * e2x + rs * e2y, u2y = rc * e2y - rs * e2x;
        const float u3x = rc * e3x + rs * e3y, u3y = rc * e3y - rs * e3x;

        // ---- pass 1: approximate distance for every token (no transcendentals)
        float dt_[KBLK];
        float dmin = 3.4e38f;
        #pragma unroll
        for (int k = 0; k < KBLK; ++k) {
            const int n = (k << 6) | lane;
            const float4 A  = ldsA[n];
            const float4 Bv = ldsB[n];
            float dx, dy;
            dx = A.x  + u0x; dy = A.y  + u0y; const float q0 = fmaf(dy, dy, dx * dx);
            dx = A.z  + u1x; dy = A.w  + u1y; const float q1 = fmaf(dy, dy, dx * dx);
            dx = Bv.x + u2x; dy = Bv.y + u2y; const float q2 = fmaf(dy, dy, dx * dx);
            dx = Bv.z + u3x; dy = Bv.w + u3y; const float q3 = fmaf(dy, dy, dx * dx);
            const float d = ((approx_sqrt(q0) + approx_sqrt(q1)) +
                             (approx_sqrt(q2) + approx_sqrt(q3)));
            dt_[k] = d;
            dmin = fminf(dmin, d);
        }
        // wave-wide min of approx distance
        #pragma unroll
        for (int off = 32; off > 0; off >>= 1)
            dmin = fminf(dmin, __shfl_xor(dmin, off, 64));
        // candidate threshold: covers (1.0342)^2 = 1.0696 worst-case approx slack
        const float thr = dmin * 1.08f;

        // ---- pass 2: exact eval only for candidate blocks
        float bestd = 3.4e38f;
        int   bestn = 0;
        #pragma unroll
        for (int k = 0; k < KBLK; ++k) {
            if (__any(dt_[k] <= thr)) {
                const int n = (k << 6) | lane;
                const float4 A  = ldsA[n];
                const float4 Bv = ldsB[n];
                float dx, dy;
                dx = A.x  + u0x; dy = A.y  + u0y; const float q0 = fmaf(dy, dy, dx * dx);
                dx = A.z  + u1x; dy = A.w  + u1y; const float q1 = fmaf(dy, dy, dx * dx);
                dx = Bv.x + u2x; dy = Bv.y + u2y; const float q2 = fmaf(dy, dy, dx * dx);
                dx = Bv.z + u3x; dy = Bv.w + u3y; const float q3 = fmaf(dy, dy, dx * dx);
                const float d = ((__builtin_amdgcn_sqrtf(q0) + __builtin_amdgcn_sqrtf(q1)) +
                                 (__builtin_amdgcn_sqrtf(q2) + __builtin_amdgcn_sqrtf(q3)));
                const bool upd = (d < bestd) || (d == bestd && n < bestn);
                bestd = upd ? d : bestd;
                bestn = upd ? n : bestn;
            }
        }

        // wave argmin reduction, lowest-index tie-break (matches jnp.argmin)
        #pragma unroll
        for (int off = 32; off > 0; off >>= 1) {
            const float od = __shfl_xor(bestd, off, 64);
            const int   on = __shfl_xor(bestn, off, 64);
            if (od < bestd || (od == bestd && on < bestn)) { bestd = od; bestn = on; }
        }

        // selected contour in global frame (same arithmetic as R1-passing version)
        const float4 A  = ldsA[bestn];
        const float4 Bv = ldsB[bestn];
        const float c0x = A.x  * rc - A.y  * rs + cpx, c0y = A.x  * rs + A.y  * rc + cpy;
        const float c1x = A.z  * rc - A.w  * rs + cpx, c1y = A.z  * rs + A.w  * rc + cpy;
        const float c2x = Bv.x * rc - Bv.y * rs + cpx, c2y = Bv.x * rs + Bv.y * rc + cpy;
        const float c3x = Bv.z * rc - Bv.w * rs + cpx, c3y = Bv.z * rs + Bv.w * rc + cpy;

        const float npx = 0.25f * (((c0x + c1x) + c2x) + c3x);
        const float npy = 0.25f * (((c0y + c1y) + c2y) + c3y);
        const float dxx = c0x - c3x, dyy = c0y - c3y;
        const float nh  = atan2f(dyy, dxx);

        if (lane == 0) {
            const int ot = b * T_STEPS + t;
            outIdx[ot]         = (float)bestn;
            outPos[2 * ot]     = npx;
            outPos[2 * ot + 1] = npy;
            outHead[ot]        = nh;
        }

        // carry for next step: rotation directly from the contour edge
        // (cos(atan2(y,x)), sin(atan2(y,x))) == (x,y)/len to ~1e-7
        cpx = npx; cpy = npy;
        const float len = __builtin_amdgcn_sqrtf(fmaf(dyy, dyy, dxx * dxx));
        rc = dxx / len;
        rs = dyy / len;
    }
}

extern "C" void kernel_launch(void* const* d_in, const int* in_sizes, int n_in,
                              void* d_out, int out_size, void* d_ws, size_t ws_size,
                              hipStream_t stream) {
    const float* data = (const float*)d_in[0];
    const float* tok  = (const float*)d_in[1];
    float* out = (float*)d_out;

    const int B = in_sizes[0] / (T_STEPS * 3);   // 4096
    const int grid = (B + WAVES_PER_BLOCK - 1) / WAVES_PER_BLOCK;

    tokenizer_kernel<<<grid, BLOCK, 0, stream>>>(data, tok, out, B);
}